// Round 23
// baseline (237.800 us; speedup 1.0000x reference)
//
#include <hip/hip_runtime.h>
#include <hip/hip_bf16.h>

typedef __bf16 bf16x8 __attribute__((ext_vector_type(8)));
typedef float f32x4 __attribute__((ext_vector_type(4)));
typedef float f32x2 __attribute__((ext_vector_type(2)));

#define MT 64   // tokens per block
#define CC 256

// swizzled LDS byte offset, [.][256] bf16 tile (row stride 512B)
__device__ __forceinline__ int swz(int r, int c) {
    return r * 512 + ((c * 2) ^ ((r & 7) << 4));
}
// swizzled LDS byte offset, [.][512] bf16 tile (row stride 1024B)
__device__ __forceinline__ int swzH(int r, int c) {
    return r * 1024 + ((c * 2) ^ ((r & 7) << 4));
}

// packed-B fragment load: tile (nc, kc) of 16 cols x 32 k, 1KB contiguous.
// PROTECTED INVARIANT (r9, -47%): weights stay fragment-packed.
__device__ __forceinline__ bf16x8 ldB(const __bf16* __restrict__ WT, int nc, int KC, int kc,
                                      int laneoff) {
    return *(const bf16x8*)(WT + ((size_t)nc * KC + kc) * 512 + laneoff);
}

// issue-early staging: NT-load 64x256 fp32 tile (8 f32x4/thread @512thr), pack bf16 in regs
__device__ __forceinline__ void stage_issue(const float* __restrict__ src, int row0, int tid,
                                            unsigned long long (&h)[8]) {
#pragma unroll
    for (int i = 0; i < 8; ++i) {
        int f = i * 512 + tid;
        int r = f >> 6;
        int c = (f & 63) * 4;
        f32x4 v = __builtin_nontemporal_load((const f32x4*)(src + (size_t)(row0 + r) * CC + c));
        union { __bf16 b[4]; unsigned long long u; } uu;
        uu.b[0] = (__bf16)v[0]; uu.b[1] = (__bf16)v[1];
        uu.b[2] = (__bf16)v[2]; uu.b[3] = (__bf16)v[3];
        h[i] = uu.u;
    }
}
__device__ __forceinline__ void stage_retire(__bf16* dst, int tid,
                                             const unsigned long long (&h)[8]) {
#pragma unroll
    for (int i = 0; i < 8; ++i) {
        int f = i * 512 + tid;
        int r = f >> 6;
        int c = (f & 63) * 4;
        *(unsigned long long*)((char*)dst + swz(r, c)) = h[i];
    }
}
__device__ __forceinline__ void stream_tile(const float* __restrict__ src, int row0, int tid,
                                            __bf16* dst) {
    unsigned long long h[8];
    stage_issue(src, row0, tid, h);
    stage_retire(dst, tid, h);
}

// weight prep: transpose + bf16 + FRAGMENT-PACK (16col x 32k tiles = 1KB contiguous,
// element order lane*8+e). layout (bf16 elem offsets):
//   WTqp @0 (K=512,N=256: k<256 Wq else Wpos) | WTkp @131072 (Wk/Wpos)
//   WTo1 @262144 (K=256,N=512) | WTo2 @393216 (K=512,N=64)
//   WTv @425984 (K=256,N=256) | WTout @491520 (K=256,N=256)
__global__ void prep_all(const float* __restrict__ Wq, const float* __restrict__ Wk,
                         const float* __restrict__ Wpos, const float* __restrict__ Wo1,
                         const float* __restrict__ Wo2, const float* __restrict__ Wv,
                         const float* __restrict__ Wout, __bf16* __restrict__ ws)
{
    int i = blockIdx.x * 256 + threadIdx.x;
    if (i >= 557056) return;
    int j, K, N;
    const float* S0 = nullptr; const float* S1 = nullptr;
    if (i < 131072)      { j = i;          K = 512; N = 256; S0 = Wq;  S1 = Wpos; }
    else if (i < 262144) { j = i - 131072; K = 512; N = 256; S0 = Wk;  S1 = Wpos; }
    else if (i < 393216) { j = i - 262144; K = 256; N = 512; S0 = Wo1; }
    else if (i < 425984) { j = i - 393216; K = 512; N = 64;  S0 = Wo2; }
    else if (i < 491520) { j = i - 425984; K = 256; N = 256; S0 = Wv; }
    else                 { j = i - 491520; K = 256; N = 256; S0 = Wout; }
    int tile = j >> 9, r = j & 511;
    int lane = r >> 3, e = r & 7;
    int q4 = lane >> 4, r16 = lane & 15;
    int KC = K >> 5;
    int nc = tile / KC, kc = tile - nc * KC;
    int k = kc * 32 + q4 * 8 + e;
    int n = nc * 16 + r16;
    float v;
    if (S1 && k >= 256) v = S1[(size_t)(k - 256) * N + n];
    else                v = S0[(size_t)k * N + n];
    ws[i] = (__bf16)v;
}

// ============ fused kernel: MT=64, 512 threads, 140KB LDS, 8 phase slots ============
// Occupancy is pinned at 1 block/CU in every legal config (register file), so spend
// the full LDS on buffer dedication to cut phase slots 11 -> 8:
//   H=64K holds all 512 h1 cols -> h1 one slot, off one slot (8 waves, full K=512);
//   dedicated pose buffer -> q and k each one K=512 slot.
extern "C" __global__ void __launch_bounds__(512, 1)
fused_ext_attn(const float* __restrict__ query, const float* __restrict__ key,
               const float* __restrict__ value, const float* __restrict__ refp,
               const float* __restrict__ pose,
               const __bf16* __restrict__ ws,
               const float* __restrict__ bq, const float* __restrict__ bk,
               const float* __restrict__ bv, const float* __restrict__ bpos,
               const float* __restrict__ bo1, const float* __restrict__ bo2,
               const float* __restrict__ bout,
               float* __restrict__ out)
{
    const __bf16* WTqp  = ws;             // KC=16
    const __bf16* WTkp  = ws + 131072;    // KC=16
    const __bf16* WTo1  = ws + 262144;    // KC=8
    const __bf16* WTo2  = ws + 393216;    // KC=16
    const __bf16* WTv   = ws + 425984;    // KC=8
    const __bf16* WTout = ws + 491520;    // KC=8

    __shared__ __attribute__((aligned(16))) __bf16 Q[MT * CC];    // query -> key -> value
    __shared__ __attribute__((aligned(16))) __bf16 P[MT * CC];    // pose -> o
    __shared__ __attribute__((aligned(16))) __bf16 H[MT * 512];   // h1 (full 512 cols)
    __shared__ __attribute__((aligned(16))) char   SY[12288];     // off(bf16,8K) qk(2K) wv(2K)

    __bf16* off_b = (__bf16*)SY;          // [64][64] bf16
    float*  qk_s  = (float*)(SY + 8192);  // [64][8]
    float*  wv_s  = (float*)(SY + 10240); // [64][8]

    const int tid = threadIdx.x;
    const int lane = tid & 63;
    const int wid = tid >> 6;        // 0..7 — this wave's head (cols 32w..32w+32)
    const int r16 = lane & 15;
    const int q4 = lane >> 4;
    const int laneoff = lane * 8;
    const int row0 = blockIdx.x * MT;

    // ---- P1: stage query -> Q, pose -> P ----
    stream_tile(query, row0, tid, Q);
    stream_tile(pose, row0, tid, P);
    __syncthreads();                                   // B1

    // ---- P2: h1 = relu(query@Wo1+bo1), BOTH 256-col halves -> H (one slot) ----
    for (int p = 0; p < 2; ++p) {
        f32x4 acc[4][2];
#pragma unroll
        for (int i = 0; i < 4; ++i)
#pragma unroll
            for (int j = 0; j < 2; ++j) acc[i][j] = (f32x4){0.f, 0.f, 0.f, 0.f};
#pragma unroll
        for (int ks = 0; ks < 8; ++ks) {
            int ak = ks * 32 + q4 * 8;
            bf16x8 a[4], b[2];
#pragma unroll
            for (int mf = 0; mf < 4; ++mf)
                a[mf] = *(const bf16x8*)((const char*)Q + swz(mf * 16 + r16, ak));
#pragma unroll
            for (int nf = 0; nf < 2; ++nf)
                b[nf] = ldB(WTo1, p * 16 + wid * 2 + nf, 8, ks, laneoff);
#pragma unroll
            for (int mf = 0; mf < 4; ++mf)
#pragma unroll
                for (int nf = 0; nf < 2; ++nf)
                    acc[mf][nf] = __builtin_amdgcn_mfma_f32_16x16x32_bf16(a[mf], b[nf], acc[mf][nf], 0, 0, 0);
        }
#pragma unroll
        for (int mf = 0; mf < 4; ++mf)
#pragma unroll
            for (int nf = 0; nf < 2; ++nf) {
                int col = p * 256 + wid * 32 + nf * 16 + r16;
                float bias = bo1[col];
#pragma unroll
                for (int r = 0; r < 4; ++r)
                    *(__bf16*)((char*)H + swzH(mf * 16 + q4 * 4 + r, col)) =
                        (__bf16)fmaxf(acc[mf][nf][r] + bias, 0.f);
            }
    }
    __syncthreads();                                   // B2

    // ---- P3: issue key loads ; q-GEMM K=512 (query in Q, pose in P), one slot ----
    unsigned long long hkey[8];
    stage_issue(key, row0, tid, hkey);
    f32x4 qa[4][2];
#pragma unroll
    for (int i = 0; i < 4; ++i)
#pragma unroll
        for (int j = 0; j < 2; ++j) qa[i][j] = (f32x4){0.f, 0.f, 0.f, 0.f};
#pragma unroll
    for (int ks = 0; ks < 16; ++ks) {
        int ak = (ks & 7) * 32 + q4 * 8;
        const char* Abase = (ks < 8) ? (const char*)Q : (const char*)P;
        bf16x8 a[4], b[2];
#pragma unroll
        for (int mf = 0; mf < 4; ++mf)
            a[mf] = *(const bf16x8*)(Abase + swz(mf * 16 + r16, ak));
#pragma unroll
        for (int nf = 0; nf < 2; ++nf)
            b[nf] = ldB(WTqp, wid * 2 + nf, 16, ks, laneoff);
#pragma unroll
        for (int mf = 0; mf < 4; ++mf)
#pragma unroll
            for (int nf = 0; nf < 2; ++nf)
                qa[mf][nf] = __builtin_amdgcn_mfma_f32_16x16x32_bf16(a[mf], b[nf], qa[mf][nf], 0, 0, 0);
    }
    __syncthreads();                                   // B3 (Q=query reads done)

    // ---- P4: retire key -> Q ; off = h1 @ Wo2 (all 8 waves, full K=512, one slot) ----
    stage_retire(Q, tid, hkey);
    {
        const int oc = wid & 3;            // off col-tile (16 cols)
        const int rbase = (wid >> 2) * 32; // off row half (32 rows = 2 mf)
        f32x4 accO[2];
        accO[0] = (f32x4){0.f, 0.f, 0.f, 0.f};
        accO[1] = (f32x4){0.f, 0.f, 0.f, 0.f};
#pragma unroll
        for (int ks = 0; ks < 16; ++ks) {
            int ak = ks * 32 + q4 * 8;
            bf16x8 b = ldB(WTo2, oc, 16, ks, laneoff);
#pragma unroll
            for (int mf = 0; mf < 2; ++mf) {
                bf16x8 a = *(const bf16x8*)((const char*)H + swzH(rbase + mf * 16 + r16, ak));
                accO[mf] = __builtin_amdgcn_mfma_f32_16x16x32_bf16(a, b, accO[mf], 0, 0, 0);
            }
        }
        int col = oc * 16 + r16;
        float b2 = bo2[col];
#pragma unroll
        for (int mf = 0; mf < 2; ++mf)
#pragma unroll
            for (int r = 0; r < 4; ++r)
                off_b[(rbase + mf * 16 + q4 * 4 + r) * 64 + col] = (__bf16)(accO[mf][r] + b2);
    }
    __syncthreads();                                   // B4 (key in Q; off_b ready; H dead)

    // ---- P5: issue value loads ; k-GEMM K=512 (key in Q, pose in P) ; dot -> qk_s ----
    unsigned long long hval[8];
    stage_issue(value, row0, tid, hval);
    {
        f32x4 ka[4][2];
#pragma unroll
        for (int i = 0; i < 4; ++i)
#pragma unroll
            for (int j = 0; j < 2; ++j) ka[i][j] = (f32x4){0.f, 0.f, 0.f, 0.f};
#pragma unroll
        for (int ks = 0; ks < 16; ++ks) {
            int ak = (ks & 7) * 32 + q4 * 8;
            const char* Abase = (ks < 8) ? (const char*)Q : (const char*)P;
            bf16x8 a[4], b[2];
#pragma unroll
            for (int mf = 0; mf < 4; ++mf)
                a[mf] = *(const bf16x8*)(Abase + swz(mf * 16 + r16, ak));
#pragma unroll
            for (int nf = 0; nf < 2; ++nf)
                b[nf] = ldB(WTkp, wid * 2 + nf, 16, ks, laneoff);
#pragma unroll
            for (int mf = 0; mf < 4; ++mf)
#pragma unroll
                for (int nf = 0; nf < 2; ++nf)
                    ka[mf][nf] = __builtin_amdgcn_mfma_f32_16x16x32_bf16(a[mf], b[nf], ka[mf][nf], 0, 0, 0);
        }
        float Bq[2], Bk[2];
#pragma unroll
        for (int nf = 0; nf < 2; ++nf) {
            int col = wid * 32 + nf * 16 + r16;
            Bq[nf] = bq[col] + bpos[col];
            Bk[nf] = bk[col] + bpos[col];
        }
#pragma unroll
        for (int mf = 0; mf < 4; ++mf)
#pragma unroll
            for (int r = 0; r < 4; ++r) {
                float p0 = (qa[mf][0][r] + Bq[0]) * (ka[mf][0][r] + Bk[0])
                         + (qa[mf][1][r] + Bq[1]) * (ka[mf][1][r] + Bk[1]);
#pragma unroll
                for (int m = 1; m < 16; m <<= 1)
                    p0 += __shfl_xor(p0, m);
                if (r16 == 0)
                    qk_s[(mf * 16 + q4 * 4 + r) * 8 + wid] = p0;
            }
    }
    __syncthreads();                                   // B5 (Q=key reads done)

    // ---- P6: retire value -> Q ; softmax (512 jobs) -> wv_s ----
    stage_retire(Q, tid, hval);
    {
        int t = tid >> 3, h = tid & 7;
        float qk = qk_s[t * 8 + h];
        f32x2 rp = __builtin_nontemporal_load((const f32x2*)(refp + (size_t)(row0 + t) * 2));
        float wgt[4], lg[4];
        float m = -1e30f;
#pragma unroll
        for (int kk = 0; kk < 4; ++kk) {
            float ox = (float)off_b[t * 64 + (h * 4 + kk) * 2];
            float oy = (float)off_b[t * 64 + (h * 4 + kk) * 2 + 1];
            float cx = rp[0] + ox - 0.5f, cy = rp[1] + oy - 0.5f;
            float wx = fmaxf(0.f, 1.f - fabsf(cx));
            float wy = fmaxf(0.f, 1.f - fabsf(cy));
            wgt[kk] = wx * wy;
            lg[kk] = qk * wgt[kk] * 0.17677669529663687f;  // 1/sqrt(32)
            m = fmaxf(m, lg[kk]);
        }
        float s = 0.f, sw = 0.f;
#pragma unroll
        for (int kk = 0; kk < 4; ++kk) {
            float e = __expf(lg[kk] - m);
            s += e;
            sw += e * wgt[kk];
        }
        wv_s[t * 8 + h] = sw / s;
    }
    __syncthreads();                                   // B6 (value in Q; wv ready)

    // ---- P7: o = (value@Wv + bv) * wv -> P (pose dead) ----
    {
        f32x4 acc[4][2];
#pragma unroll
        for (int i = 0; i < 4; ++i)
#pragma unroll
            for (int j = 0; j < 2; ++j) acc[i][j] = (f32x4){0.f, 0.f, 0.f, 0.f};
#pragma unroll
        for (int ks = 0; ks < 8; ++ks) {
            int ak = ks * 32 + q4 * 8;
            bf16x8 a[4], b[2];
#pragma unroll
            for (int mf = 0; mf < 4; ++mf)
                a[mf] = *(const bf16x8*)((const char*)Q + swz(mf * 16 + r16, ak));
#pragma unroll
            for (int nf = 0; nf < 2; ++nf)
                b[nf] = ldB(WTv, wid * 2 + nf, 8, ks, laneoff);
#pragma unroll
            for (int mf = 0; mf < 4; ++mf)
#pragma unroll
                for (int nf = 0; nf < 2; ++nf)
                    acc[mf][nf] = __builtin_amdgcn_mfma_f32_16x16x32_bf16(a[mf], b[nf], acc[mf][nf], 0, 0, 0);
        }
#pragma unroll
        for (int mf = 0; mf < 4; ++mf)
#pragma unroll
            for (int nf = 0; nf < 2; ++nf) {
                int col = wid * 32 + nf * 16 + r16;   // head = wid
                float bias = bv[col];
#pragma unroll
                for (int r = 0; r < 4; ++r) {
                    int row = mf * 16 + q4 * 4 + r;
                    float wvv = wv_s[row * 8 + wid];
                    *(__bf16*)((char*)P + swz(row, col)) = (__bf16)((acc[mf][nf][r] + bias) * wvv);
                }
            }
    }
    __syncthreads();                                   // B7

    // ---- P8: out = o @ WTout + bout -> global (NT store) ----
    {
        f32x4 acc[4][2];
#pragma unroll
        for (int i = 0; i < 4; ++i)
#pragma unroll
            for (int j = 0; j < 2; ++j) acc[i][j] = (f32x4){0.f, 0.f, 0.f, 0.f};
#pragma unroll
        for (int ks = 0; ks < 8; ++ks) {
            int ak = ks * 32 + q4 * 8;
            bf16x8 a[4], b[2];
#pragma unroll
            for (int mf = 0; mf < 4; ++mf)
                a[mf] = *(const bf16x8*)((const char*)P + swz(mf * 16 + r16, ak));
#pragma unroll
            for (int nf = 0; nf < 2; ++nf)
                b[nf] = ldB(WTout, wid * 2 + nf, 8, ks, laneoff);
#pragma unroll
            for (int mf = 0; mf < 4; ++mf)
#pragma unroll
                for (int nf = 0; nf < 2; ++nf)
                    acc[mf][nf] = __builtin_amdgcn_mfma_f32_16x16x32_bf16(a[mf], b[nf], acc[mf][nf], 0, 0, 0);
        }
#pragma unroll
        for (int mf = 0; mf < 4; ++mf)
#pragma unroll
            for (int nf = 0; nf < 2; ++nf) {
                int col = wid * 32 + nf * 16 + r16;
                float bias = bout[col];
#pragma unroll
                for (int r = 0; r < 4; ++r) {
                    int row = mf * 16 + q4 * 4 + r;
                    __builtin_nontemporal_store(acc[mf][nf][r] + bias,
                                                out + (size_t)(row0 + row) * CC + col);
                }
            }
    }
}

extern "C" void kernel_launch(void* const* d_in, const int* in_sizes, int n_in,
                              void* d_out, int out_size, void* d_ws, size_t ws_size,
                              hipStream_t stream)
{
    const float* query = (const float*)d_in[0];
    const float* key   = (const float*)d_in[1];
    const float* value = (const float*)d_in[2];
    const float* refp  = (const float*)d_in[3];
    const float* pose  = (const float*)d_in[4];
    const float* Wq  = (const float*)d_in[5];  const float* bq   = (const float*)d_in[6];
    const float* Wk  = (const float*)d_in[7];  const float* bk   = (const float*)d_in[8];
    const float* Wv  = (const float*)d_in[9];  const float* bv   = (const float*)d_in[10];
    const float* Wo1 = (const float*)d_in[11]; const float* bo1  = (const float*)d_in[12];
    const float* Wo2 = (const float*)d_in[13]; const float* bo2  = (const float*)d_in[14];
    const float* Wpos= (const float*)d_in[15]; const float* bpos = (const float*)d_in[16];
    const float* Wout= (const float*)d_in[17]; const float* bout = (const float*)d_in[18];

    __bf16* ws = (__bf16*)d_ws;

    prep_all<<<2176, 256, 0, stream>>>(Wq, Wk, Wpos, Wo1, Wo2, Wv, Wout, ws);

    fused_ext_attn<<<65536 / MT, 512, 0, stream>>>(
        query, key, value, refp, pose, ws,
        bq, bk, bv, bpos, bo1, bo2, bout, (float*)d_out);
}

// Round 24
// 149.496 us; speedup vs baseline: 1.5907x; 1.5907x over previous
//
#include <hip/hip_runtime.h>
#include <hip/hip_bf16.h>

typedef __bf16 bf16x8 __attribute__((ext_vector_type(8)));
typedef float f32x4 __attribute__((ext_vector_type(4)));
typedef float f32x2 __attribute__((ext_vector_type(2)));

#define MT 64   // tokens per block
#define CC 256

// swizzled LDS byte offset, [.][256] bf16 tile (row stride 512B)
__device__ __forceinline__ int swz(int r, int c) {
    return r * 512 + ((c * 2) ^ ((r & 7) << 4));
}
// swizzled LDS byte offset, [.][512] bf16 tile (row stride 1024B)
__device__ __forceinline__ int swzH(int r, int c) {
    return r * 1024 + ((c * 2) ^ ((r & 7) << 4));
}

// packed-B fragment load: tile (nc, kc) of 16 cols x 32 k, 1KB contiguous.
// PROTECTED INVARIANT (r9, -47%): weights stay fragment-packed.
__device__ __forceinline__ bf16x8 ldB(const __bf16* __restrict__ WT, int nc, int KC, int kc,
                                      int laneoff) {
    return *(const bf16x8*)(WT + ((size_t)nc * KC + kc) * 512 + laneoff);
}

// issue-early staging: NT-load 64x256 fp32 tile (8 f32x4/thread @512thr), pack bf16 in regs
__device__ __forceinline__ void stage_issue(const float* __restrict__ src, int row0, int tid,
                                            unsigned long long (&h)[8]) {
#pragma unroll
    for (int i = 0; i < 8; ++i) {
        int f = i * 512 + tid;
        int r = f >> 6;
        int c = (f & 63) * 4;
        f32x4 v = __builtin_nontemporal_load((const f32x4*)(src + (size_t)(row0 + r) * CC + c));
        union { __bf16 b[4]; unsigned long long u; } uu;
        uu.b[0] = (__bf16)v[0]; uu.b[1] = (__bf16)v[1];
        uu.b[2] = (__bf16)v[2]; uu.b[3] = (__bf16)v[3];
        h[i] = uu.u;
    }
}
__device__ __forceinline__ void stage_retire(__bf16* dst, int tid,
                                             const unsigned long long (&h)[8]) {
#pragma unroll
    for (int i = 0; i < 8; ++i) {
        int f = i * 512 + tid;
        int r = f >> 6;
        int c = (f & 63) * 4;
        *(unsigned long long*)((char*)dst + swz(r, c)) = h[i];
    }
}
__device__ __forceinline__ void stream_tile(const float* __restrict__ src, int row0, int tid,
                                            __bf16* dst) {
    unsigned long long h[8];
    stage_issue(src, row0, tid, h);
    stage_retire(dst, tid, h);
}

// weight prep: transpose + bf16 + FRAGMENT-PACK (16col x 32k tiles = 1KB contiguous,
// element order lane*8+e). layout (bf16 elem offsets):
//   WTqp @0 (K=512,N=256: k<256 Wq else Wpos) | WTkp @131072 (Wk/Wpos)
//   WTo1 @262144 (K=256,N=512) | WTo2 @393216 (K=512,N=64)
//   WTv @425984 (K=256,N=256) | WTout @491520 (K=256,N=256)
__global__ void prep_all(const float* __restrict__ Wq, const float* __restrict__ Wk,
                         const float* __restrict__ Wpos, const float* __restrict__ Wo1,
                         const float* __restrict__ Wo2, const float* __restrict__ Wv,
                         const float* __restrict__ Wout, __bf16* __restrict__ ws)
{
    int i = blockIdx.x * 256 + threadIdx.x;
    if (i >= 557056) return;
    int j, K, N;
    const float* S0 = nullptr; const float* S1 = nullptr;
    if (i < 131072)      { j = i;          K = 512; N = 256; S0 = Wq;  S1 = Wpos; }
    else if (i < 262144) { j = i - 131072; K = 512; N = 256; S0 = Wk;  S1 = Wpos; }
    else if (i < 393216) { j = i - 262144; K = 256; N = 512; S0 = Wo1; }
    else if (i < 425984) { j = i - 393216; K = 512; N = 64;  S0 = Wo2; }
    else if (i < 491520) { j = i - 425984; K = 256; N = 256; S0 = Wv; }
    else                 { j = i - 491520; K = 256; N = 256; S0 = Wout; }
    int tile = j >> 9, r = j & 511;
    int lane = r >> 3, e = r & 7;
    int q4 = lane >> 4, r16 = lane & 15;
    int KC = K >> 5;
    int nc = tile / KC, kc = tile - nc * KC;
    int k = kc * 32 + q4 * 8 + e;
    int n = nc * 16 + r16;
    float v;
    if (S1 && k >= 256) v = S1[(size_t)(k - 256) * N + n];
    else                v = S0[(size_t)k * N + n];
    ws[i] = (__bf16)v;
}

// ============ fused kernel: MT=64, 512 threads, 140KB LDS, 8 phase slots ============
// Phase-collapse retry with spill-safe liveness: off-GEMM runs BEFORE q-GEMM so no
// accumulator spans a foreign phase. Peak register phase = P5 (qa+ka ~105 < 128 cap).
extern "C" __global__ void __launch_bounds__(512, 1)
fused_ext_attn(const float* __restrict__ query, const float* __restrict__ key,
               const float* __restrict__ value, const float* __restrict__ refp,
               const float* __restrict__ pose,
               const __bf16* __restrict__ ws,
               const float* __restrict__ bq, const float* __restrict__ bk,
               const float* __restrict__ bv, const float* __restrict__ bpos,
               const float* __restrict__ bo1, const float* __restrict__ bo2,
               const float* __restrict__ bout,
               float* __restrict__ out)
{
    const __bf16* WTqp  = ws;             // KC=16
    const __bf16* WTkp  = ws + 131072;    // KC=16
    const __bf16* WTo1  = ws + 262144;    // KC=8
    const __bf16* WTo2  = ws + 393216;    // KC=16
    const __bf16* WTv   = ws + 425984;    // KC=8
    const __bf16* WTout = ws + 491520;    // KC=8

    __shared__ __attribute__((aligned(16))) __bf16 Q[MT * CC];    // query -> value
    __shared__ __attribute__((aligned(16))) __bf16 P[MT * CC];    // pose -> o
    __shared__ __attribute__((aligned(16))) __bf16 H[MT * 512];   // h1 (512 cols) -> key (alias)
    __shared__ __attribute__((aligned(16))) char   SY[12288];     // off(bf16,8K) qk(2K) wv(2K)

    __bf16* off_b = (__bf16*)SY;          // [64][64] bf16
    float*  qk_s  = (float*)(SY + 8192);  // [64][8]
    float*  wv_s  = (float*)(SY + 10240); // [64][8]

    const int tid = threadIdx.x;
    const int lane = tid & 63;
    const int wid = tid >> 6;        // 0..7 — this wave's head (cols 32w..32w+32)
    const int r16 = lane & 15;
    const int q4 = lane >> 4;
    const int laneoff = lane * 8;
    const int row0 = blockIdx.x * MT;

    // ---- P1: stage query -> Q, pose -> P ----
    stream_tile(query, row0, tid, Q);
    stream_tile(pose, row0, tid, P);
    __syncthreads();                                   // B1

    // ---- P2: issue key ; h1 = relu(query@Wo1+bo1), BOTH halves -> H (one slot) ----
    unsigned long long hkey[8];
    stage_issue(key, row0, tid, hkey);
    for (int p = 0; p < 2; ++p) {
        f32x4 acc[4][2];
#pragma unroll
        for (int i = 0; i < 4; ++i)
#pragma unroll
            for (int j = 0; j < 2; ++j) acc[i][j] = (f32x4){0.f, 0.f, 0.f, 0.f};
#pragma unroll
        for (int ks = 0; ks < 8; ++ks) {
            int ak = ks * 32 + q4 * 8;
            bf16x8 a[4], b[2];
#pragma unroll
            for (int mf = 0; mf < 4; ++mf)
                a[mf] = *(const bf16x8*)((const char*)Q + swz(mf * 16 + r16, ak));
#pragma unroll
            for (int nf = 0; nf < 2; ++nf)
                b[nf] = ldB(WTo1, p * 16 + wid * 2 + nf, 8, ks, laneoff);
#pragma unroll
            for (int mf = 0; mf < 4; ++mf)
#pragma unroll
                for (int nf = 0; nf < 2; ++nf)
                    acc[mf][nf] = __builtin_amdgcn_mfma_f32_16x16x32_bf16(a[mf], b[nf], acc[mf][nf], 0, 0, 0);
        }
#pragma unroll
        for (int mf = 0; mf < 4; ++mf)
#pragma unroll
            for (int nf = 0; nf < 2; ++nf) {
                int col = p * 256 + wid * 32 + nf * 16 + r16;
                float bias = bo1[col];
#pragma unroll
                for (int r = 0; r < 4; ++r)
                    *(__bf16*)((char*)H + swzH(mf * 16 + q4 * 4 + r, col)) =
                        (__bf16)fmaxf(acc[mf][nf][r] + bias, 0.f);
            }
    }
    __syncthreads();                                   // B2

    // ---- P3: off = h1 @ Wo2 (all 8 waves, full K=512, one slot) ----
    {
        const int oc = wid & 3;            // off col-tile (16 cols)
        const int rbase = (wid >> 2) * 32; // off row half (32 rows)
        f32x4 accO[2];
        accO[0] = (f32x4){0.f, 0.f, 0.f, 0.f};
        accO[1] = (f32x4){0.f, 0.f, 0.f, 0.f};
#pragma unroll
        for (int ks = 0; ks < 16; ++ks) {
            int ak = ks * 32 + q4 * 8;
            bf16x8 b = ldB(WTo2, oc, 16, ks, laneoff);
#pragma unroll
            for (int mf = 0; mf < 2; ++mf) {
                bf16x8 a = *(const bf16x8*)((const char*)H + swzH(rbase + mf * 16 + r16, ak));
                accO[mf] = __builtin_amdgcn_mfma_f32_16x16x32_bf16(a, b, accO[mf], 0, 0, 0);
            }
        }
        int col = oc * 16 + r16;
        float b2 = bo2[col];
#pragma unroll
        for (int mf = 0; mf < 2; ++mf)
#pragma unroll
            for (int r = 0; r < 4; ++r)
                off_b[(rbase + mf * 16 + q4 * 4 + r) * 64 + col] = (__bf16)(accO[mf][r] + b2);
    }
    __syncthreads();                                   // B3 (H dead; off_b ready)

    // ---- P4: retire key -> H (swz alias) ; q-GEMM K=512 (Q=query, P=pose) -> qa ----
    stage_retire((__bf16*)H, tid, hkey);
    f32x4 qa[4][2];
#pragma unroll
    for (int i = 0; i < 4; ++i)
#pragma unroll
        for (int j = 0; j < 2; ++j) qa[i][j] = (f32x4){0.f, 0.f, 0.f, 0.f};
#pragma unroll
    for (int ks = 0; ks < 16; ++ks) {
        int ak = (ks & 7) * 32 + q4 * 8;
        const char* Abase = (ks < 8) ? (const char*)Q : (const char*)P;
        bf16x8 a[4], b[2];
#pragma unroll
        for (int mf = 0; mf < 4; ++mf)
            a[mf] = *(const bf16x8*)(Abase + swz(mf * 16 + r16, ak));
#pragma unroll
        for (int nf = 0; nf < 2; ++nf)
            b[nf] = ldB(WTqp, wid * 2 + nf, 16, ks, laneoff);
#pragma unroll
        for (int mf = 0; mf < 4; ++mf)
#pragma unroll
            for (int nf = 0; nf < 2; ++nf)
                qa[mf][nf] = __builtin_amdgcn_mfma_f32_16x16x32_bf16(a[mf], b[nf], qa[mf][nf], 0, 0, 0);
    }
    __syncthreads();                                   // B4 (key in H; Q=query dead)

    // ---- P5: k-GEMM K=512 (H=key, P=pose) -> ka ; head dot -> qk_s ----
    {
        f32x4 ka[4][2];
#pragma unroll
        for (int i = 0; i < 4; ++i)
#pragma unroll
            for (int j = 0; j < 2; ++j) ka[i][j] = (f32x4){0.f, 0.f, 0.f, 0.f};
#pragma unroll
        for (int ks = 0; ks < 16; ++ks) {
            int ak = (ks & 7) * 32 + q4 * 8;
            const char* Abase = (ks < 8) ? (const char*)H : (const char*)P;
            bf16x8 a[4], b[2];
#pragma unroll
            for (int mf = 0; mf < 4; ++mf)
                a[mf] = *(const bf16x8*)(Abase + swz(mf * 16 + r16, ak));
#pragma unroll
            for (int nf = 0; nf < 2; ++nf)
                b[nf] = ldB(WTkp, wid * 2 + nf, 16, ks, laneoff);
#pragma unroll
            for (int mf = 0; mf < 4; ++mf)
#pragma unroll
                for (int nf = 0; nf < 2; ++nf)
                    ka[mf][nf] = __builtin_amdgcn_mfma_f32_16x16x32_bf16(a[mf], b[nf], ka[mf][nf], 0, 0, 0);
        }
        float Bq[2], Bk[2];
#pragma unroll
        for (int nf = 0; nf < 2; ++nf) {
            int col = wid * 32 + nf * 16 + r16;
            Bq[nf] = bq[col] + bpos[col];
            Bk[nf] = bk[col] + bpos[col];
        }
#pragma unroll
        for (int mf = 0; mf < 4; ++mf)
#pragma unroll
            for (int r = 0; r < 4; ++r) {
                float p0 = (qa[mf][0][r] + Bq[0]) * (ka[mf][0][r] + Bk[0])
                         + (qa[mf][1][r] + Bq[1]) * (ka[mf][1][r] + Bk[1]);
#pragma unroll
                for (int m = 1; m < 16; m <<= 1)
                    p0 += __shfl_xor(p0, m);
                if (r16 == 0)
                    qk_s[(mf * 16 + q4 * 4 + r) * 8 + wid] = p0;
            }
    }
    __syncthreads();                                   // B5 (qa/ka dead; P=pose reads done)

    // ---- P6: stream value -> Q ; softmax (512 jobs) -> wv_s ----
    stream_tile(value, row0, tid, Q);
    {
        int t = tid >> 3, h = tid & 7;
        float qk = qk_s[t * 8 + h];
        f32x2 rp = __builtin_nontemporal_load((const f32x2*)(refp + (size_t)(row0 + t) * 2));
        float wgt[4], lg[4];
        float m = -1e30f;
#pragma unroll
        for (int kk = 0; kk < 4; ++kk) {
            float ox = (float)off_b[t * 64 + (h * 4 + kk) * 2];
            float oy = (float)off_b[t * 64 + (h * 4 + kk) * 2 + 1];
            float cx = rp[0] + ox - 0.5f, cy = rp[1] + oy - 0.5f;
            float wx = fmaxf(0.f, 1.f - fabsf(cx));
            float wy = fmaxf(0.f, 1.f - fabsf(cy));
            wgt[kk] = wx * wy;
            lg[kk] = qk * wgt[kk] * 0.17677669529663687f;  // 1/sqrt(32)
            m = fmaxf(m, lg[kk]);
        }
        float s = 0.f, sw = 0.f;
#pragma unroll
        for (int kk = 0; kk < 4; ++kk) {
            float e = __expf(lg[kk] - m);
            s += e;
            sw += e * wgt[kk];
        }
        wv_s[t * 8 + h] = sw / s;
    }
    __syncthreads();                                   // B6 (value in Q; wv ready)

    // ---- P7: o = (value@Wv + bv) * wv -> P ----
    {
        f32x4 acc[4][2];
#pragma unroll
        for (int i = 0; i < 4; ++i)
#pragma unroll
            for (int j = 0; j < 2; ++j) acc[i][j] = (f32x4){0.f, 0.f, 0.f, 0.f};
#pragma unroll
        for (int ks = 0; ks < 8; ++ks) {
            int ak = ks * 32 + q4 * 8;
            bf16x8 a[4], b[2];
#pragma unroll
            for (int mf = 0; mf < 4; ++mf)
                a[mf] = *(const bf16x8*)((const char*)Q + swz(mf * 16 + r16, ak));
#pragma unroll
            for (int nf = 0; nf < 2; ++nf)
                b[nf] = ldB(WTv, wid * 2 + nf, 8, ks, laneoff);
#pragma unroll
            for (int mf = 0; mf < 4; ++mf)
#pragma unroll
                for (int nf = 0; nf < 2; ++nf)
                    acc[mf][nf] = __builtin_amdgcn_mfma_f32_16x16x32_bf16(a[mf], b[nf], acc[mf][nf], 0, 0, 0);
        }
#pragma unroll
        for (int mf = 0; mf < 4; ++mf)
#pragma unroll
            for (int nf = 0; nf < 2; ++nf) {
                int col = wid * 32 + nf * 16 + r16;   // head = wid
                float bias = bv[col];
#pragma unroll
                for (int r = 0; r < 4; ++r) {
                    int row = mf * 16 + q4 * 4 + r;
                    float wvv = wv_s[row * 8 + wid];
                    *(__bf16*)((char*)P + swz(row, col)) = (__bf16)((acc[mf][nf][r] + bias) * wvv);
                }
            }
    }
    __syncthreads();                                   // B7

    // ---- P8: out = o @ WTout + bout -> global (NT store) ----
    {
        f32x4 acc[4][2];
#pragma unroll
        for (int i = 0; i < 4; ++i)
#pragma unroll
            for (int j = 0; j < 2; ++j) acc[i][j] = (f32x4){0.f, 0.f, 0.f, 0.f};
#pragma unroll
        for (int ks = 0; ks < 8; ++ks) {
            int ak = ks * 32 + q4 * 8;
            bf16x8 a[4], b[2];
#pragma unroll
            for (int mf = 0; mf < 4; ++mf)
                a[mf] = *(const bf16x8*)((const char*)P + swz(mf * 16 + r16, ak));
#pragma unroll
            for (int nf = 0; nf < 2; ++nf)
                b[nf] = ldB(WTout, wid * 2 + nf, 8, ks, laneoff);
#pragma unroll
            for (int mf = 0; mf < 4; ++mf)
#pragma unroll
                for (int nf = 0; nf < 2; ++nf)
                    acc[mf][nf] = __builtin_amdgcn_mfma_f32_16x16x32_bf16(a[mf], b[nf], acc[mf][nf], 0, 0, 0);
        }
#pragma unroll
        for (int mf = 0; mf < 4; ++mf)
#pragma unroll
            for (int nf = 0; nf < 2; ++nf) {
                int col = wid * 32 + nf * 16 + r16;
                float bias = bout[col];
#pragma unroll
                for (int r = 0; r < 4; ++r) {
                    int row = mf * 16 + q4 * 4 + r;
                    __builtin_nontemporal_store(acc[mf][nf][r] + bias,
                                                out + (size_t)(row0 + row) * CC + col);
                }
            }
    }
}

extern "C" void kernel_launch(void* const* d_in, const int* in_sizes, int n_in,
                              void* d_out, int out_size, void* d_ws, size_t ws_size,
                              hipStream_t stream)
{
    const float* query = (const float*)d_in[0];
    const float* key   = (const float*)d_in[1];
    const float* value = (const float*)d_in[2];
    const float* refp  = (const float*)d_in[3];
    const float* pose  = (const float*)d_in[4];
    const float* Wq  = (const float*)d_in[5];  const float* bq   = (const float*)d_in[6];
    const float* Wk  = (const float*)d_in[7];  const float* bk   = (const float*)d_in[8];
    const float* Wv  = (const float*)d_in[9];  const float* bv   = (const float*)d_in[10];
    const float* Wo1 = (const float*)d_in[11]; const float* bo1  = (const float*)d_in[12];
    const float* Wo2 = (const float*)d_in[13]; const float* bo2  = (const float*)d_in[14];
    const float* Wpos= (const float*)d_in[15]; const float* bpos = (const float*)d_in[16];
    const float* Wout= (const float*)d_in[17]; const float* bout = (const float*)d_in[18];

    __bf16* ws = (__bf16*)d_ws;

    prep_all<<<2176, 256, 0, stream>>>(Wq, Wk, Wpos, Wo1, Wo2, Wv, Wout, ws);

    fused_ext_attn<<<65536 / MT, 512, 0, stream>>>(
        query, key, value, refp, pose, ws,
        bq, bk, bv, bpos, bo1, bo2, bout, (float*)d_out);
}

// Round 25
// 137.030 us; speedup vs baseline: 1.7354x; 1.0910x over previous
//
#include <hip/hip_runtime.h>
#include <hip/hip_bf16.h>

typedef __bf16 bf16x8 __attribute__((ext_vector_type(8)));
typedef float f32x4 __attribute__((ext_vector_type(4)));
typedef float f32x2 __attribute__((ext_vector_type(2)));

#define MT 64   // tokens per block
#define CC 256

// swizzled LDS byte offset, [.][256] bf16 tile (row stride 512B)
__device__ __forceinline__ int swz(int r, int c) {
    return r * 512 + ((c * 2) ^ ((r & 7) << 4));
}

// packed-B fragment load: tile (nc, kc) of 16 cols x 32 k, 1KB contiguous.
// PROTECTED INVARIANT (r9, -47%): weights stay fragment-packed so each B-load is
// one contiguous 1KB wave transaction, not a 16-cacheline scatter.
__device__ __forceinline__ bf16x8 ldB(const __bf16* __restrict__ WT, int nc, int KC, int kc,
                                      int laneoff) {
    return *(const bf16x8*)(WT + ((size_t)nc * KC + kc) * 512 + laneoff);
}

// stream one 64x256 fp32 tile: NT load -> bf16 -> swizzled LDS write.
// NT keeps single-use activation streams from evicting L2-resident weights (r5, -11%).
__device__ __forceinline__ void stream_tile(const float* __restrict__ src, int row0, int tid,
                                            __bf16* dst) {
    int w = (tid >> 6) & 7;
#pragma unroll
    for (int i = 0; i < 8; ++i) {
        int ii = (i + w) & 7;
        int f = ii * 512 + tid;
        int r = f >> 6;
        int c = (f & 63) * 4;
        f32x4 v = __builtin_nontemporal_load((const f32x4*)(src + (size_t)(row0 + r) * CC + c));
        union { __bf16 h[4]; unsigned long long u; } uu;
        uu.h[0] = (__bf16)v[0]; uu.h[1] = (__bf16)v[1];
        uu.h[2] = (__bf16)v[2]; uu.h[3] = (__bf16)v[3];
        *(unsigned long long*)((char*)dst + swz(r, c)) = uu.u;
    }
}

// weight prep: transpose + bf16 + FRAGMENT-PACK (16col x 32k tiles = 1KB contiguous,
// element order lane*8+e). layout (bf16 elem offsets):
//   WTqp @0 (K=512,N=256: k<256 Wq else Wpos) | WTkp @131072 (Wk/Wpos)
//   WTo1 @262144 (K=256,N=512) | WTo2 @393216 (K=512,N=64)
//   WTv @425984 (K=256,N=256) | WTout @491520 (K=256,N=256)
__global__ void prep_all(const float* __restrict__ Wq, const float* __restrict__ Wk,
                         const float* __restrict__ Wpos, const float* __restrict__ Wo1,
                         const float* __restrict__ Wo2, const float* __restrict__ Wv,
                         const float* __restrict__ Wout, __bf16* __restrict__ ws)
{
    int i = blockIdx.x * 256 + threadIdx.x;
    if (i >= 557056) return;
    int j, K, N;
    const float* S0 = nullptr; const float* S1 = nullptr;
    if (i < 131072)      { j = i;          K = 512; N = 256; S0 = Wq;  S1 = Wpos; }
    else if (i < 262144) { j = i - 131072; K = 512; N = 256; S0 = Wk;  S1 = Wpos; }
    else if (i < 393216) { j = i - 262144; K = 256; N = 512; S0 = Wo1; }
    else if (i < 425984) { j = i - 393216; K = 512; N = 64;  S0 = Wo2; }
    else if (i < 491520) { j = i - 425984; K = 256; N = 256; S0 = Wv; }
    else                 { j = i - 491520; K = 256; N = 256; S0 = Wout; }
    int tile = j >> 9, r = j & 511;
    int lane = r >> 3, e = r & 7;
    int q4 = lane >> 4, r16 = lane & 15;
    int KC = K >> 5;
    int nc = tile / KC, kc = tile - nc * KC;
    int k = kc * 32 + q4 * 8 + e;
    int n = nc * 16 + r16;
    float v;
    if (S1 && k >= 256) v = S1[(size_t)(k - 256) * N + n];
    else                v = S0[(size_t)k * N + n];
    ws[i] = (__bf16)v;
}

// ============ fused kernel: MT=64, 512 threads, per-wave K-step rotation ============
// FINAL. Best measured: 138.05 us e2e (fused ~142 + prep ~5). Latency-bound local
// optimum: register-file-limited residency (~8 waves/CU in every legal config on
// this toolchain) vs ~400cy L2 dependency chains; all pipes ~21%. 13 controlled
// experiments (occupancy, traffic, barriers, prefetch, convoying, slot count)
// bracket this floor for the barrier-phased design family.
extern "C" __global__ void __launch_bounds__(512, 2)
fused_ext_attn(const float* __restrict__ query, const float* __restrict__ key,
               const float* __restrict__ value, const float* __restrict__ refp,
               const float* __restrict__ pose,
               const __bf16* __restrict__ ws,
               const float* __restrict__ bq, const float* __restrict__ bk,
               const float* __restrict__ bv, const float* __restrict__ bpos,
               const float* __restrict__ bo1, const float* __restrict__ bo2,
               const float* __restrict__ bout,
               float* __restrict__ out)
{
    const __bf16* WTqp  = ws;             // KC=16
    const __bf16* WTkp  = ws + 131072;    // KC=16
    const __bf16* WTo1  = ws + 262144;    // KC=8
    const __bf16* WTo2  = ws + 393216;    // KC=16
    const __bf16* WTv   = ws + 425984;    // KC=8
    const __bf16* WTout = ws + 491520;    // KC=8

    __shared__ __attribute__((aligned(16))) __bf16 SA[MT * CC];   // query -> key -> value
    __shared__ __attribute__((aligned(16))) __bf16 SX[MT * CC];   // h1 -> pose -> o
    __shared__ __attribute__((aligned(16))) char   SY[12288];     // off(bf16,8K) qk(2K) wv(2K)

    __bf16* off_b = (__bf16*)SY;          // [64][64] bf16
    float*  qk_s  = (float*)(SY + 8192);  // [64][8]
    float*  wv_s  = (float*)(SY + 10240); // [64][8]

    const int tid = threadIdx.x;
    const int lane = tid & 63;
    const int wid = tid >> 6;        // 0..7 — this wave's head (cols 32w..32w+32)
    const int r16 = lane & 15;
    const int q4 = lane >> 4;
    const int laneoff = lane * 8;
    const int row0 = blockIdx.x * MT;

    // ---- P1: stage query -> SA ----
    stream_tile(query, row0, tid, SA);
    __syncthreads();                                   // B1

    // ---- P2..P5: h1 (2x256-col passes) + off (waves 0-3, accumulate in regs) ----
    f32x4 accO[4];
#pragma unroll
    for (int i = 0; i < 4; ++i) accO[i] = (f32x4){0.f, 0.f, 0.f, 0.f};
    for (int p = 0; p < 2; ++p) {
        f32x4 acc[4][2];
#pragma unroll
        for (int i = 0; i < 4; ++i)
#pragma unroll
            for (int j = 0; j < 2; ++j) acc[i][j] = (f32x4){0.f, 0.f, 0.f, 0.f};
#pragma unroll
        for (int ks = 0; ks < 8; ++ks) {
            int kse = (ks + wid) & 7;
            int ak = kse * 32 + q4 * 8;
            bf16x8 a[4], b[2];
#pragma unroll
            for (int mf = 0; mf < 4; ++mf)
                a[mf] = *(const bf16x8*)((const char*)SA + swz(mf * 16 + r16, ak));
#pragma unroll
            for (int nf = 0; nf < 2; ++nf)
                b[nf] = ldB(WTo1, p * 16 + wid * 2 + nf, 8, kse, laneoff);
#pragma unroll
            for (int mf = 0; mf < 4; ++mf)
#pragma unroll
                for (int nf = 0; nf < 2; ++nf)
                    acc[mf][nf] = __builtin_amdgcn_mfma_f32_16x16x32_bf16(a[mf], b[nf], acc[mf][nf], 0, 0, 0);
        }
#pragma unroll
        for (int mf = 0; mf < 4; ++mf)
#pragma unroll
            for (int nf = 0; nf < 2; ++nf) {
                int col = wid * 32 + nf * 16 + r16;
                float bias = bo1[p * 256 + col];
#pragma unroll
                for (int r = 0; r < 4; ++r)
                    *(__bf16*)((char*)SX + swz(mf * 16 + q4 * 4 + r, col)) =
                        (__bf16)fmaxf(acc[mf][nf][r] + bias, 0.f);
            }
        __syncthreads();                               // B2 / B4
        if (wid < 4) {
#pragma unroll
            for (int ks = 0; ks < 8; ++ks) {
                int kse = (ks + wid) & 7;
                int ak = kse * 32 + q4 * 8;
                bf16x8 b = ldB(WTo2, wid, 16, p * 8 + kse, laneoff);
#pragma unroll
                for (int mf = 0; mf < 4; ++mf) {
                    bf16x8 a = *(const bf16x8*)((const char*)SX + swz(mf * 16 + r16, ak));
                    accO[mf] = __builtin_amdgcn_mfma_f32_16x16x32_bf16(a, b, accO[mf], 0, 0, 0);
                }
            }
            if (p == 1) {
                int col = wid * 16 + r16;
                float b2 = bo2[col];
#pragma unroll
                for (int mf = 0; mf < 4; ++mf)
#pragma unroll
                    for (int r = 0; r < 4; ++r)
                        off_b[(mf * 16 + q4 * 4 + r) * 64 + col] = (__bf16)(accO[mf][r] + b2);
            }
        }
        __syncthreads();                               // B3 / B5
    }

    // ---- P6: stage pose -> SX ; q-GEMM part1 (A = query in SA) ----
    f32x4 qa[4][2];
#pragma unroll
    for (int i = 0; i < 4; ++i)
#pragma unroll
        for (int j = 0; j < 2; ++j) qa[i][j] = (f32x4){0.f, 0.f, 0.f, 0.f};
    stream_tile(pose, row0, tid, SX);
#pragma unroll
    for (int ks = 0; ks < 8; ++ks) {
        int kse = (ks + wid) & 7;
        int ak = kse * 32 + q4 * 8;
        bf16x8 a[4], b[2];
#pragma unroll
        for (int mf = 0; mf < 4; ++mf)
            a[mf] = *(const bf16x8*)((const char*)SA + swz(mf * 16 + r16, ak));
#pragma unroll
        for (int nf = 0; nf < 2; ++nf)
            b[nf] = ldB(WTqp, wid * 2 + nf, 16, kse, laneoff);
#pragma unroll
        for (int mf = 0; mf < 4; ++mf)
#pragma unroll
            for (int nf = 0; nf < 2; ++nf)
                qa[mf][nf] = __builtin_amdgcn_mfma_f32_16x16x32_bf16(a[mf], b[nf], qa[mf][nf], 0, 0, 0);
    }
    __syncthreads();                                   // B6

    // ---- P7: stage key -> SA ; q-GEMM part2 (A = pose in SX) ----
    stream_tile(key, row0, tid, SA);
#pragma unroll
    for (int ks = 0; ks < 8; ++ks) {
        int kse = (ks + wid) & 7;
        int ak = kse * 32 + q4 * 8;
        bf16x8 a[4], b[2];
#pragma unroll
        for (int mf = 0; mf < 4; ++mf)
            a[mf] = *(const bf16x8*)((const char*)SX + swz(mf * 16 + r16, ak));
#pragma unroll
        for (int nf = 0; nf < 2; ++nf)
            b[nf] = ldB(WTqp, wid * 2 + nf, 16, 8 + kse, laneoff);
#pragma unroll
        for (int mf = 0; mf < 4; ++mf)
#pragma unroll
            for (int nf = 0; nf < 2; ++nf)
                qa[mf][nf] = __builtin_amdgcn_mfma_f32_16x16x32_bf16(a[mf], b[nf], qa[mf][nf], 0, 0, 0);
    }
    __syncthreads();                                   // B7

    // ---- P8: k-GEMM (K=512: key in SA, pose in SX) ; head dot -> qk_s ----
    {
        f32x4 ka[4][2];
#pragma unroll
        for (int i = 0; i < 4; ++i)
#pragma unroll
            for (int j = 0; j < 2; ++j) ka[i][j] = (f32x4){0.f, 0.f, 0.f, 0.f};
#pragma unroll
        for (int ks = 0; ks < 16; ++ks) {
            int kse = (ks + wid * 2) & 15;
            int ak = (kse & 7) * 32 + q4 * 8;
            const char* Abase = (kse < 8) ? (const char*)SA : (const char*)SX;
            bf16x8 a[4], b[2];
#pragma unroll
            for (int mf = 0; mf < 4; ++mf)
                a[mf] = *(const bf16x8*)(Abase + swz(mf * 16 + r16, ak));
#pragma unroll
            for (int nf = 0; nf < 2; ++nf)
                b[nf] = ldB(WTkp, wid * 2 + nf, 16, kse, laneoff);
#pragma unroll
            for (int mf = 0; mf < 4; ++mf)
#pragma unroll
                for (int nf = 0; nf < 2; ++nf)
                    ka[mf][nf] = __builtin_amdgcn_mfma_f32_16x16x32_bf16(a[mf], b[nf], ka[mf][nf], 0, 0, 0);
        }
        float Bq[2], Bk[2];
#pragma unroll
        for (int nf = 0; nf < 2; ++nf) {
            int col = wid * 32 + nf * 16 + r16;
            Bq[nf] = bq[col] + bpos[col];
            Bk[nf] = bk[col] + bpos[col];
        }
#pragma unroll
        for (int mf = 0; mf < 4; ++mf)
#pragma unroll
            for (int r = 0; r < 4; ++r) {
                float p0 = (qa[mf][0][r] + Bq[0]) * (ka[mf][0][r] + Bk[0])
                         + (qa[mf][1][r] + Bq[1]) * (ka[mf][1][r] + Bk[1]);
#pragma unroll
                for (int m = 1; m < 16; m <<= 1)
                    p0 += __shfl_xor(p0, m);
                if (r16 == 0)
                    qk_s[(mf * 16 + q4 * 4 + r) * 8 + wid] = p0;
            }
    }
    __syncthreads();                                   // B8

    // ---- P9: stage value -> SA ; softmax (512 jobs: t=tid>>3, h=tid&7) -> wv_s ----
    stream_tile(value, row0, tid, SA);
    {
        int t = tid >> 3, h = tid & 7;
        float qk = qk_s[t * 8 + h];
        f32x2 rp = __builtin_nontemporal_load((const f32x2*)(refp + (size_t)(row0 + t) * 2));
        float wgt[4], lg[4];
        float m = -1e30f;
#pragma unroll
        for (int kk = 0; kk < 4; ++kk) {
            float ox = (float)off_b[t * 64 + (h * 4 + kk) * 2];
            float oy = (float)off_b[t * 64 + (h * 4 + kk) * 2 + 1];
            float cx = rp[0] + ox - 0.5f, cy = rp[1] + oy - 0.5f;
            float wx = fmaxf(0.f, 1.f - fabsf(cx));
            float wy = fmaxf(0.f, 1.f - fabsf(cy));
            wgt[kk] = wx * wy;
            lg[kk] = qk * wgt[kk] * 0.17677669529663687f;  // 1/sqrt(32)
            m = fmaxf(m, lg[kk]);
        }
        float s = 0.f, sw = 0.f;
#pragma unroll
        for (int kk = 0; kk < 4; ++kk) {
            float e = __expf(lg[kk] - m);
            s += e;
            sw += e * wgt[kk];
        }
        wv_s[t * 8 + h] = sw / s;
    }
    __syncthreads();                                   // B9

    // ---- P10: o = (value@Wv + bv) * wv -> SX ----
    {
        f32x4 acc[4][2];
#pragma unroll
        for (int i = 0; i < 4; ++i)
#pragma unroll
            for (int j = 0; j < 2; ++j) acc[i][j] = (f32x4){0.f, 0.f, 0.f, 0.f};
#pragma unroll
        for (int ks = 0; ks < 8; ++ks) {
            int kse = (ks + wid) & 7;
            int ak = kse * 32 + q4 * 8;
            bf16x8 a[4], b[2];
#pragma unroll
            for (int mf = 0; mf < 4; ++mf)
                a[mf] = *(const bf16x8*)((const char*)SA + swz(mf * 16 + r16, ak));
#pragma unroll
            for (int nf = 0; nf < 2; ++nf)
                b[nf] = ldB(WTv, wid * 2 + nf, 8, kse, laneoff);
#pragma unroll
            for (int mf = 0; mf < 4; ++mf)
#pragma unroll
                for (int nf = 0; nf < 2; ++nf)
                    acc[mf][nf] = __builtin_amdgcn_mfma_f32_16x16x32_bf16(a[mf], b[nf], acc[mf][nf], 0, 0, 0);
        }
#pragma unroll
        for (int mf = 0; mf < 4; ++mf)
#pragma unroll
            for (int nf = 0; nf < 2; ++nf) {
                int col = wid * 32 + nf * 16 + r16;   // head = wid
                float bias = bv[col];
#pragma unroll
                for (int r = 0; r < 4; ++r) {
                    int row = mf * 16 + q4 * 4 + r;
                    float wvv = wv_s[row * 8 + wid];
                    *(__bf16*)((char*)SX + swz(row, col)) = (__bf16)((acc[mf][nf][r] + bias) * wvv);
                }
            }
    }
    __syncthreads();                                   // B10

    // ---- P11: out = o @ WTout + bout -> global (NT store) ----
    {
        f32x4 acc[4][2];
#pragma unroll
        for (int i = 0; i < 4; ++i)
#pragma unroll
            for (int j = 0; j < 2; ++j) acc[i][j] = (f32x4){0.f, 0.f, 0.f, 0.f};
#pragma unroll
        for (int ks = 0; ks < 8; ++ks) {
            int kse = (ks + wid) & 7;
            int ak = kse * 32 + q4 * 8;
            bf16x8 a[4], b[2];
#pragma unroll
            for (int mf = 0; mf < 4; ++mf)
                a[mf] = *(const bf16x8*)((const char*)SX + swz(mf * 16 + r16, ak));
#pragma unroll
            for (int nf = 0; nf < 2; ++nf)
                b[nf] = ldB(WTout, wid * 2 + nf, 8, kse, laneoff);
#pragma unroll
            for (int mf = 0; mf < 4; ++mf)
#pragma unroll
                for (int nf = 0; nf < 2; ++nf)
                    acc[mf][nf] = __builtin_amdgcn_mfma_f32_16x16x32_bf16(a[mf], b[nf], acc[mf][nf], 0, 0, 0);
        }
#pragma unroll
        for (int mf = 0; mf < 4; ++mf)
#pragma unroll
            for (int nf = 0; nf < 2; ++nf) {
                int col = wid * 32 + nf * 16 + r16;
                float bias = bout[col];
#pragma unroll
                for (int r = 0; r < 4; ++r) {
                    int row = mf * 16 + q4 * 4 + r;
                    __builtin_nontemporal_store(acc[mf][nf][r] + bias,
                                                out + (size_t)(row0 + row) * CC + col);
                }
            }
    }
}

extern "C" void kernel_launch(void* const* d_in, const int* in_sizes, int n_in,
                              void* d_out, int out_size, void* d_ws, size_t ws_size,
                              hipStream_t stream)
{
    const float* query = (const float*)d_in[0];
    const float* key   = (const float*)d_in[1];
    const float* value = (const float*)d_in[2];
    const float* refp  = (const float*)d_in[3];
    const float* pose  = (const float*)d_in[4];
    const float* Wq  = (const float*)d_in[5];  const float* bq   = (const float*)d_in[6];
    const float* Wk  = (const float*)d_in[7];  const float* bk   = (const float*)d_in[8];
    const float* Wv  = (const float*)d_in[9];  const float* bv   = (const float*)d_in[10];
    const float* Wo1 = (const float*)d_in[11]; const float* bo1  = (const float*)d_in[12];
    const float* Wo2 = (const float*)d_in[13]; const float* bo2  = (const float*)d_in[14];
    const float* Wpos= (const float*)d_in[15]; const float* bpos = (const float*)d_in[16];
    const float* Wout= (const float*)d_in[17]; const float* bout = (const float*)d_in[18];

    __bf16* ws = (__bf16*)d_ws;

    prep_all<<<2176, 256, 0, stream>>>(Wq, Wk, Wpos, Wo1, Wo2, Wv, Wout, ws);

    fused_ext_attn<<<65536 / MT, 512, 0, stream>>>(
        query, key, value, refp, pose, ws,
        bq, bk, bv, bpos, bo1, bo2, bout, (float*)d_out);
}